// Round 17
// baseline (537.846 us; speedup 1.0000x reference)
//
#include <hip/hip_runtime.h>
#include <hip/hip_bf16.h>

#define B_    32
#define N_    6
#define D_    41
#define C_    64
#define FH_   4
#define FW_   6
#define INCH  768
#define HW    24
#define O_    105
#define PBN   984
#define PPB   5904
#define NPTS  188928
#define FINAL_ELEMS 81920000

// ws: depth f32[NPTS] | feat f32[192*1536] | vox i32[NPTS]

// ---------------------------------------------------------------------------
// K1: exact f32 1x1-conv GEMM + softmax(D) -> depth/feat ws, logits f32 out.
// ---------------------------------------------------------------------------
__global__ __launch_bounds__(256) void k_conv(
    const float* __restrict__ x, const float* __restrict__ w,
    const float* __restrict__ bias,
    float* __restrict__ depth_ws, float* __restrict__ feat_ws,
    float* __restrict__ dlogit)          // f32! (192,41,24) at out+81.92M
{
    const int bn = blockIdx.x;
    const int t  = threadIdx.x;
    __shared__ float ylds[O_ * HW];
    __shared__ float smax[HW], srs[HW];

    const float* xb0 = x + (size_t)bn * (INCH * HW);
    for (int u2 = t; u2 < O_ * 6; u2 += 256) {
        int o  = u2 / 6;
        int hq = (u2 % 6) * 4;
        const float* wr = w + (size_t)o * INCH;
        const float* xb = xb0 + hq;
        float a0 = 0.f, a1 = 0.f, a2 = 0.f, a3 = 0.f;
        for (int c = 0; c < INCH; ++c) {
            float wv = wr[c];
            float4 xv = *(const float4*)(xb + c * HW);
            a0 = __fadd_rn(a0, __fmul_rn(wv, xv.x));
            a1 = __fadd_rn(a1, __fmul_rn(wv, xv.y));
            a2 = __fadd_rn(a2, __fmul_rn(wv, xv.z));
            a3 = __fadd_rn(a3, __fmul_rn(wv, xv.w));
        }
        float bo = bias[o];
        ylds[o * HW + hq + 0] = __fadd_rn(a0, bo);
        ylds[o * HW + hq + 1] = __fadd_rn(a1, bo);
        ylds[o * HW + hq + 2] = __fadd_rn(a2, bo);
        ylds[o * HW + hq + 3] = __fadd_rn(a3, bo);
    }
    __syncthreads();

    if (t < HW) {
        float mx = -1e30f;
        for (int d = 0; d < D_; d++) mx = fmaxf(mx, ylds[d * HW + t]);
        float s = 0.f;
        for (int d = 0; d < D_; d++) s = __fadd_rn(s, expf(__fsub_rn(ylds[d * HW + t], mx)));
        smax[t] = mx; srs[t] = s;
    }
    __syncthreads();

    for (int u = t; u < D_ * HW; u += 256) {
        float yv = ylds[u];
        int hw = u % HW;
        depth_ws[bn * PBN + u] = __fdiv_rn(expf(__fsub_rn(yv, smax[hw])), srs[hw]);
        dlogit[(size_t)bn * PBN + u] = yv;           // graded chunk 1 (f32)
    }
    for (int u = t; u < C_ * HW; u += 256)
        feat_ws[bn * (C_ * HW) + u] = ylds[D_ * HW + u];
}

// ---------------------------------------------------------------------------
// K2: geometry, f32-faithful (strti2 inverse, FMA combine, sequential einsum).
// vox = ix*200 + iy or -1.
// ---------------------------------------------------------------------------
__global__ __launch_bounds__(256) void k_geom(
    const float* __restrict__ m1, const float* __restrict__ trans,
    const float* __restrict__ m2, int* __restrict__ vox)
{
    const float* rots = (fabsf(m1[0]) > 50.0f) ? m2 : m1;
    const float* intr = (fabsf(m1[0]) > 50.0f) ? m1 : m2;

    int p = blockIdx.x * 256 + threadIdx.x;   // 738*256 == 188928
    int b  = p / PPB;
    int pl = p % PPB;
    int n  = pl / PBN;
    int r  = pl % PBN;
    int d  = r / HW;
    int hw = r % HW;
    int h = hw / FW_, wp = hw % FW_;

    float dv = 4.0f + (float)d;
    float xi = (float)((double)wp * (199.0 / 5.0));
    float yi = (float)((double)h  * (149.0 / 3.0));
    float px = __fmul_rn(xi, dv), py = __fmul_rn(yi, dv), pz = dv;

    int bn = b * N_ + n;
    const float* K = intr + bn * 9;
    const float* R = rots + bn * 9;
    const float* T = trans + bn * 3;

    float a00 = K[0], a01 = K[1], a02 = K[2];
    float a11 = K[4], a12 = K[5];
    float a22 = K[8];

    // LAPACK strti2 (upper triangular) exact f32 sequence
    float i00 = __fdiv_rn(1.0f, a00);
    float i11 = __fdiv_rn(1.0f, a11);
    float x0  = __fmul_rn(a01, i00);
    float i01 = __fmul_rn(-i11, x0);
    float i22 = __fdiv_rn(1.0f, a22);
    float y0  = __fmul_rn(a02, i00);
    y0 = __fadd_rn(y0, __fmul_rn(a12, i01));
    float y1  = __fmul_rn(a12, i11);
    float i02 = __fmul_rn(-i22, y0);
    float i12 = __fmul_rn(-i22, y1);
    float i10 = 0.f, i20 = 0.f, i21 = 0.f;

    float r00 = R[0], r01 = R[1], r02 = R[2];
    float r10 = R[3], r11 = R[4], r12 = R[5];
    float r20 = R[6], r21 = R[7], r22 = R[8];

#define MM(u0,u1,u2, v0,v1,v2) \
    __fmaf_rn(u2, v2, __fmaf_rn(u1, v1, __fmul_rn(u0, v0)))
    float c00 = MM(r00, r01, r02, i00, i10, i20);
    float c01 = MM(r00, r01, r02, i01, i11, i21);
    float c02 = MM(r00, r01, r02, i02, i12, i22);
    float c10 = MM(r10, r11, r12, i00, i10, i20);
    float c11 = MM(r10, r11, r12, i01, i11, i21);
    float c12 = MM(r10, r11, r12, i02, i12, i22);
    float c20 = MM(r20, r21, r22, i00, i10, i20);
    float c21 = MM(r20, r21, r22, i01, i11, i21);
    float c22 = MM(r20, r21, r22, i02, i12, i22);
#undef MM

#define DOT3(u0,v0,u1,v1,u2,v2) \
    __fadd_rn(__fadd_rn(__fmul_rn(u0,v0), __fmul_rn(u1,v1)), __fmul_rn(u2,v2))
    float gx = __fadd_rn(DOT3(c00,px, c01,py, c02,pz), T[0]);
    float gy = __fadd_rn(DOT3(c10,px, c11,py, c12,pz), T[1]);
    float gz = __fadd_rn(DOT3(c20,px, c21,py, c22,pz), T[2]);
#undef DOT3

    int ix = (int)__fmul_rn(__fadd_rn(gx, 50.0f), 2.0f);
    int iy = (int)__fmul_rn(__fadd_rn(gy, 50.0f), 2.0f);
    int iz = (int)__fdiv_rn(__fadd_rn(gz, 10.0f), 20.0f);
    bool kept = (ix >= 0) && (ix < 200) && (iy >= 0) && (iy < 200) && (iz == 0);
    vox[p] = kept ? (ix * 200 + iy) : -1;
}

// ---------------------------------------------------------------------------
// K3: splat -> FLOAT32 output. One block per (b, c, quarter-plane); 40KB LDS
// plane; LDS atomics; coalesced float4 stores.
// ---------------------------------------------------------------------------
__global__ __launch_bounds__(256) void k_splat(
    const float* __restrict__ depth, const float* __restrict__ feat,
    const int* __restrict__ vox, float* __restrict__ out)
{
    __shared__ float plane[10000];
    int bid = blockIdx.x;
    int b   = bid >> 8;
    int rem = bid & 255;
    int c   = rem >> 2;
    int q   = rem & 3;
    int t   = threadIdx.x;

    for (int i = t; i < 10000; i += 256) plane[i] = 0.f;
    __syncthreads();

    const int lo = q * 10000;
    const float* fb = feat + (size_t)(b * N_) * (C_ * HW) + c * HW;
    for (int i = t; i < PPB; i += 256) {
        int p = b * PPB + i;
        int rel = vox[p] - lo;
        if ((unsigned)rel < 10000u) {
            int n  = i / PBN;
            int hw = i % HW;              // 984 % 24 == 0
            atomicAdd(&plane[rel], depth[p] * fb[n * (C_ * HW) + hw]);
        }
    }
    __syncthreads();

    float4* ob = (float4*)(out + ((size_t)(b * C_ + c) * 40000) + lo);
    const float4* pl4 = (const float4*)plane;
    for (int i = t; i < 2500; i += 256) ob[i] = pl4[i];
}

// ---------------------------------------------------------------------------
extern "C" void kernel_launch(void* const* d_in, const int* in_sizes, int n_in,
                              void* d_out, int out_size, void* d_ws, size_t ws_size,
                              hipStream_t stream) {
    const float *x = nullptr, *m1 = nullptr, *m2 = nullptr, *trn = nullptr,
                *w = nullptr, *bias = nullptr;
    for (int i = 0; i < n_in; i++) {
        const float* p = (const float*)d_in[i];
        switch (in_sizes[i]) {
            case 3538944: x = p; break;
            case 1728:    if (!m1) m1 = p; else m2 = p; break;
            case 576:     trn = p; break;
            case 80640:   w = p; break;
            case 105:     bias = p; break;
            default: break;
        }
    }
    if (!x)    x    = (const float*)d_in[0];
    if (!m1)   m1   = (const float*)d_in[1];
    if (!trn)  trn  = (const float*)d_in[2];
    if (!m2)   m2   = (const float*)d_in[3];
    if (!w)    w    = (const float*)d_in[4];
    if (!bias) bias = (const float*)d_in[5];

    float* depth_ws = (float*)d_ws;
    float* feat_ws  = depth_ws + NPTS;
    int*   vox      = (int*)(feat_ws + 192 * C_ * HW);

    float* out    = (float*)d_out;            // FLOAT32 output buffer
    float* dlogit = out + FINAL_ELEMS;        // chunk 1: depth_logit (f32)

    k_conv <<<192,  256, 0, stream>>>(x, w, bias, depth_ws, feat_ws, dlogit);
    k_geom <<<738,  256, 0, stream>>>(m1, trn, m2, vox);
    k_splat<<<8192, 256, 0, stream>>>(depth_ws, feat_ws, vox, out);
}

// Round 18
// 520.130 us; speedup vs baseline: 1.0341x; 1.0341x over previous
//
#include <hip/hip_runtime.h>
#include <hip/hip_bf16.h>

#define B_    32
#define N_    6
#define D_    41
#define C_    64
#define FH_   4
#define FW_   6
#define INCH  768
#define HW    24
#define O_    105
#define PBN   984
#define PPB   5904
#define NPTS  188928
#define YSTR  2520          // O_*HW per image
#define FINAL_ELEMS 81920000

// ws: y f32[192*2520] | depth f32[NPTS] | vox i32[NPTS]

// ---------------------------------------------------------------------------
// K1a: conv y = w@x + b. Grid 576 = 192 images x 3 o-parts (35 rows each).
// Identical per-item op order to the validated exact-f32 conv.
// ---------------------------------------------------------------------------
__global__ __launch_bounds__(256) void k_conv_y(
    const float* __restrict__ x, const float* __restrict__ w,
    const float* __restrict__ bias, float* __restrict__ y_ws)
{
    const int bid  = blockIdx.x;
    const int bn   = bid / 3;
    const int part = bid % 3;
    const int t    = threadIdx.x;
    if (t >= 210) return;                   // 210 items = 35 o x 6 hw-quads
    const int u2 = part * 210 + t;
    const int o  = u2 / 6;
    const int hq = (u2 % 6) * 4;

    const float* wr = w + (size_t)o * INCH;
    const float* xb = x + (size_t)bn * (INCH * HW) + hq;
    float a0 = 0.f, a1 = 0.f, a2 = 0.f, a3 = 0.f;
    for (int c = 0; c < INCH; ++c) {
        float wv = wr[c];
        float4 xv = *(const float4*)(xb + c * HW);
        a0 = __fadd_rn(a0, __fmul_rn(wv, xv.x));
        a1 = __fadd_rn(a1, __fmul_rn(wv, xv.y));
        a2 = __fadd_rn(a2, __fmul_rn(wv, xv.z));
        a3 = __fadd_rn(a3, __fmul_rn(wv, xv.w));
    }
    float bo = bias[o];
    float* dst = y_ws + (size_t)bn * YSTR + o * HW + hq;
    dst[0] = __fadd_rn(a0, bo);
    dst[1] = __fadd_rn(a1, bo);
    dst[2] = __fadd_rn(a2, bo);
    dst[3] = __fadd_rn(a3, bo);
}

// ---------------------------------------------------------------------------
// K1b: softmax over D per (bn,hw) -> depth ws; logits f32 -> out chunk 1.
// ---------------------------------------------------------------------------
__global__ __launch_bounds__(256) void k_softmax(
    const float* __restrict__ y_ws,
    float* __restrict__ depth_ws, float* __restrict__ dlogit)
{
    const int bn = blockIdx.x;
    const int t  = threadIdx.x;
    __shared__ float smax[HW], srs[HW];
    const float* yb = y_ws + (size_t)bn * YSTR;

    if (t < HW) {
        float mx = -1e30f;
        for (int d = 0; d < D_; d++) mx = fmaxf(mx, yb[d * HW + t]);
        float s = 0.f;
        for (int d = 0; d < D_; d++) s = __fadd_rn(s, expf(__fsub_rn(yb[d * HW + t], mx)));
        smax[t] = mx; srs[t] = s;
    }
    __syncthreads();

    for (int u = t; u < D_ * HW; u += 256) {
        float yv = yb[u];
        int hw = u % HW;
        depth_ws[bn * PBN + u] = __fdiv_rn(expf(__fsub_rn(yv, smax[hw])), srs[hw]);
        dlogit[(size_t)bn * PBN + u] = yv;
    }
}

// ---------------------------------------------------------------------------
// K2: geometry, f32-faithful (validated). vox = ix*200 + iy or -1.
// ---------------------------------------------------------------------------
__global__ __launch_bounds__(256) void k_geom(
    const float* __restrict__ m1, const float* __restrict__ trans,
    const float* __restrict__ m2, int* __restrict__ vox)
{
    const float* rots = (fabsf(m1[0]) > 50.0f) ? m2 : m1;
    const float* intr = (fabsf(m1[0]) > 50.0f) ? m1 : m2;

    int p = blockIdx.x * 256 + threadIdx.x;   // 738*256 == 188928
    int b  = p / PPB;
    int pl = p % PPB;
    int n  = pl / PBN;
    int r  = pl % PBN;
    int d  = r / HW;
    int hw = r % HW;
    int h = hw / FW_, wp = hw % FW_;

    float dv = 4.0f + (float)d;
    float xi = (float)((double)wp * (199.0 / 5.0));
    float yi = (float)((double)h  * (149.0 / 3.0));
    float px = __fmul_rn(xi, dv), py = __fmul_rn(yi, dv), pz = dv;

    int bn = b * N_ + n;
    const float* K = intr + bn * 9;
    const float* R = rots + bn * 9;
    const float* T = trans + bn * 3;

    float a00 = K[0], a01 = K[1], a02 = K[2];
    float a11 = K[4], a12 = K[5];
    float a22 = K[8];

    float i00 = __fdiv_rn(1.0f, a00);
    float i11 = __fdiv_rn(1.0f, a11);
    float x0  = __fmul_rn(a01, i00);
    float i01 = __fmul_rn(-i11, x0);
    float i22 = __fdiv_rn(1.0f, a22);
    float y0  = __fmul_rn(a02, i00);
    y0 = __fadd_rn(y0, __fmul_rn(a12, i01));
    float y1  = __fmul_rn(a12, i11);
    float i02 = __fmul_rn(-i22, y0);
    float i12 = __fmul_rn(-i22, y1);
    float i10 = 0.f, i20 = 0.f, i21 = 0.f;

    float r00 = R[0], r01 = R[1], r02 = R[2];
    float r10 = R[3], r11 = R[4], r12 = R[5];
    float r20 = R[6], r21 = R[7], r22 = R[8];

#define MM(u0,u1,u2, v0,v1,v2) \
    __fmaf_rn(u2, v2, __fmaf_rn(u1, v1, __fmul_rn(u0, v0)))
    float c00 = MM(r00, r01, r02, i00, i10, i20);
    float c01 = MM(r00, r01, r02, i01, i11, i21);
    float c02 = MM(r00, r01, r02, i02, i12, i22);
    float c10 = MM(r10, r11, r12, i00, i10, i20);
    float c11 = MM(r10, r11, r12, i01, i11, i21);
    float c12 = MM(r10, r11, r12, i02, i12, i22);
    float c20 = MM(r20, r21, r22, i00, i10, i20);
    float c21 = MM(r20, r21, r22, i01, i11, i21);
    float c22 = MM(r20, r21, r22, i02, i12, i22);
#undef MM

#define DOT3(u0,v0,u1,v1,u2,v2) \
    __fadd_rn(__fadd_rn(__fmul_rn(u0,v0), __fmul_rn(u1,v1)), __fmul_rn(u2,v2))
    float gx = __fadd_rn(DOT3(c00,px, c01,py, c02,pz), T[0]);
    float gy = __fadd_rn(DOT3(c10,px, c11,py, c12,pz), T[1]);
    float gz = __fadd_rn(DOT3(c20,px, c21,py, c22,pz), T[2]);
#undef DOT3

    int ix = (int)__fmul_rn(__fadd_rn(gx, 50.0f), 2.0f);
    int iy = (int)__fmul_rn(__fadd_rn(gy, 50.0f), 2.0f);
    int iz = (int)__fdiv_rn(__fadd_rn(gz, 10.0f), 20.0f);
    bool kept = (ix >= 0) && (ix < 200) && (iy >= 0) && (iy < 200) && (iz == 0);
    vox[p] = kept ? (ix * 200 + iy) : -1;
}

// ---------------------------------------------------------------------------
// K3: splat -> f32 out. One block per (b, c, quarter-plane); 40KB LDS plane;
// LDS atomics; coalesced float4 stores. feat read directly from y rows 41+.
// ---------------------------------------------------------------------------
__global__ __launch_bounds__(256) void k_splat(
    const float* __restrict__ depth, const float* __restrict__ y_ws,
    const int* __restrict__ vox, float* __restrict__ out)
{
    __shared__ float plane[10000];
    int bid = blockIdx.x;
    int b   = bid >> 8;
    int rem = bid & 255;
    int c   = rem >> 2;
    int q   = rem & 3;
    int t   = threadIdx.x;

    for (int i = t; i < 10000; i += 256) plane[i] = 0.f;
    __syncthreads();

    const int lo = q * 10000;
    // feat[n][c][hw] = y[bn][41+c][hw]
    const float* fb = y_ws + (size_t)(b * N_) * YSTR + (D_ + c) * HW;
    for (int i = t; i < PPB; i += 256) {
        int p = b * PPB + i;
        int rel = vox[p] - lo;
        if ((unsigned)rel < 10000u) {
            int n  = i / PBN;
            int hw = i % HW;              // 984 % 24 == 0
            atomicAdd(&plane[rel], depth[p] * fb[n * YSTR + hw]);
        }
    }
    __syncthreads();

    float4* ob = (float4*)(out + ((size_t)(b * C_ + c) * 40000) + lo);
    const float4* pl4 = (const float4*)plane;
    for (int i = t; i < 2500; i += 256) ob[i] = pl4[i];
}

// ---------------------------------------------------------------------------
extern "C" void kernel_launch(void* const* d_in, const int* in_sizes, int n_in,
                              void* d_out, int out_size, void* d_ws, size_t ws_size,
                              hipStream_t stream) {
    const float *x = nullptr, *m1 = nullptr, *m2 = nullptr, *trn = nullptr,
                *w = nullptr, *bias = nullptr;
    for (int i = 0; i < n_in; i++) {
        const float* p = (const float*)d_in[i];
        switch (in_sizes[i]) {
            case 3538944: x = p; break;
            case 1728:    if (!m1) m1 = p; else m2 = p; break;
            case 576:     trn = p; break;
            case 80640:   w = p; break;
            case 105:     bias = p; break;
            default: break;
        }
    }
    if (!x)    x    = (const float*)d_in[0];
    if (!m1)   m1   = (const float*)d_in[1];
    if (!trn)  trn  = (const float*)d_in[2];
    if (!m2)   m2   = (const float*)d_in[3];
    if (!w)    w    = (const float*)d_in[4];
    if (!bias) bias = (const float*)d_in[5];

    float* y_ws     = (float*)d_ws;                 // 192*2520 f32
    float* depth_ws = y_ws + 192 * YSTR;            // NPTS f32
    int*   vox      = (int*)(depth_ws + NPTS);      // NPTS i32

    float* out    = (float*)d_out;
    float* dlogit = out + FINAL_ELEMS;

    k_conv_y <<<576,  256, 0, stream>>>(x, w, bias, y_ws);
    k_softmax<<<192,  256, 0, stream>>>(y_ws, depth_ws, dlogit);
    k_geom   <<<738,  256, 0, stream>>>(m1, trn, m2, vox);
    k_splat  <<<8192, 256, 0, stream>>>(depth_ws, y_ws, vox, out);
}

// Round 19
// 458.529 us; speedup vs baseline: 1.1730x; 1.1343x over previous
//
#include <hip/hip_runtime.h>
#include <hip/hip_bf16.h>

#define B_    32
#define N_    6
#define D_    41
#define C_    64
#define FH_   4
#define FW_   6
#define INCH  768
#define HW    24
#define O_    105
#define PBN   984
#define PPB   5904
#define NPTS  188928
#define FINAL_ELEMS 81920000

// ws: feat f32[192*1536] | depth f32[NPTS] | vox i32[NPTS]

// ---------------------------------------------------------------------------
// K1: fused conv + softmax. One block per image. x[bn] staged to LDS in two
// 36KB halves; each thread computes 3 output rows x 4 hw cols with fmaf
// (value-level changes only — binning lives in k_geom, which is bit-frozen).
// Epilogue: softmax over D in-block; depth->ws, logits->out, feat->ws.
// ---------------------------------------------------------------------------
__global__ __launch_bounds__(256) void k_conv_fused(
    const float* __restrict__ x, const float* __restrict__ w,
    const float* __restrict__ bias,
    float* __restrict__ feat_ws, float* __restrict__ depth_ws,
    float* __restrict__ dlogit)
{
    __shared__ float xs[9216];      // half of x[bn]: 384 c x 24 hw (36 KB)
    __shared__ float ys[O_ * HW];   // full y image (10 KB)
    __shared__ float smax[HW], srs[HW];

    const int bn = blockIdx.x;
    const int t  = threadIdx.x;
    const int og = t / 6;           // 35 groups x 3 rows = 105
    const int q6 = t % 6;           // hw quad

    float a[3][4] = {{0.f,0.f,0.f,0.f},{0.f,0.f,0.f,0.f},{0.f,0.f,0.f,0.f}};
    const int o0 = og * 3;
    const float4* wr0 = (const float4*)(w + (size_t)(o0 + 0) * INCH);
    const float4* wr1 = (const float4*)(w + (size_t)(o0 + 1) * INCH);
    const float4* wr2 = (const float4*)(w + (size_t)(o0 + 2) * INCH);
    float4* xs4 = (float4*)xs;

    for (int half = 0; half < 2; ++half) {
        if (half) __syncthreads();                 // drain half-0 readers
        const float4* xg = (const float4*)(x + (size_t)bn * (INCH * HW)) + half * 2304;
        for (int i = t; i < 2304; i += 256) xs4[i] = xg[i];
        __syncthreads();

        if (t < 210) {
            const int wb = half * 96;              // float4 index into w row
            for (int c4 = 0; c4 < 96; ++c4) {
                float4 w0 = wr0[wb + c4];
                float4 w1 = wr1[wb + c4];
                float4 w2 = wr2[wb + c4];
                int cb = c4 * 4;
                float4 x0 = xs4[(cb + 0) * 6 + q6];
                float4 x1 = xs4[(cb + 1) * 6 + q6];
                float4 x2 = xs4[(cb + 2) * 6 + q6];
                float4 x3 = xs4[(cb + 3) * 6 + q6];
                a[0][0]=fmaf(w0.x,x0.x,a[0][0]); a[0][1]=fmaf(w0.x,x0.y,a[0][1]);
                a[0][2]=fmaf(w0.x,x0.z,a[0][2]); a[0][3]=fmaf(w0.x,x0.w,a[0][3]);
                a[1][0]=fmaf(w1.x,x0.x,a[1][0]); a[1][1]=fmaf(w1.x,x0.y,a[1][1]);
                a[1][2]=fmaf(w1.x,x0.z,a[1][2]); a[1][3]=fmaf(w1.x,x0.w,a[1][3]);
                a[2][0]=fmaf(w2.x,x0.x,a[2][0]); a[2][1]=fmaf(w2.x,x0.y,a[2][1]);
                a[2][2]=fmaf(w2.x,x0.z,a[2][2]); a[2][3]=fmaf(w2.x,x0.w,a[2][3]);
                a[0][0]=fmaf(w0.y,x1.x,a[0][0]); a[0][1]=fmaf(w0.y,x1.y,a[0][1]);
                a[0][2]=fmaf(w0.y,x1.z,a[0][2]); a[0][3]=fmaf(w0.y,x1.w,a[0][3]);
                a[1][0]=fmaf(w1.y,x1.x,a[1][0]); a[1][1]=fmaf(w1.y,x1.y,a[1][1]);
                a[1][2]=fmaf(w1.y,x1.z,a[1][2]); a[1][3]=fmaf(w1.y,x1.w,a[1][3]);
                a[2][0]=fmaf(w2.y,x1.x,a[2][0]); a[2][1]=fmaf(w2.y,x1.y,a[2][1]);
                a[2][2]=fmaf(w2.y,x1.z,a[2][2]); a[2][3]=fmaf(w2.y,x1.w,a[2][3]);
                a[0][0]=fmaf(w0.z,x2.x,a[0][0]); a[0][1]=fmaf(w0.z,x2.y,a[0][1]);
                a[0][2]=fmaf(w0.z,x2.z,a[0][2]); a[0][3]=fmaf(w0.z,x2.w,a[0][3]);
                a[1][0]=fmaf(w1.z,x2.x,a[1][0]); a[1][1]=fmaf(w1.z,x2.y,a[1][1]);
                a[1][2]=fmaf(w1.z,x2.z,a[1][2]); a[1][3]=fmaf(w1.z,x2.w,a[1][3]);
                a[2][0]=fmaf(w2.z,x2.x,a[2][0]); a[2][1]=fmaf(w2.z,x2.y,a[2][1]);
                a[2][2]=fmaf(w2.z,x2.z,a[2][2]); a[2][3]=fmaf(w2.z,x2.w,a[2][3]);
                a[0][0]=fmaf(w0.w,x3.x,a[0][0]); a[0][1]=fmaf(w0.w,x3.y,a[0][1]);
                a[0][2]=fmaf(w0.w,x3.z,a[0][2]); a[0][3]=fmaf(w0.w,x3.w,a[0][3]);
                a[1][0]=fmaf(w1.w,x3.x,a[1][0]); a[1][1]=fmaf(w1.w,x3.y,a[1][1]);
                a[1][2]=fmaf(w1.w,x3.z,a[1][2]); a[1][3]=fmaf(w1.w,x3.w,a[1][3]);
                a[2][0]=fmaf(w2.w,x3.x,a[2][0]); a[2][1]=fmaf(w2.w,x3.y,a[2][1]);
                a[2][2]=fmaf(w2.w,x3.z,a[2][2]); a[2][3]=fmaf(w2.w,x3.w,a[2][3]);
            }
        }
    }

    if (t < 210) {
#pragma unroll
        for (int r = 0; r < 3; r++) {
            float bo = bias[o0 + r];
#pragma unroll
            for (int j = 0; j < 4; j++)
                ys[(o0 + r) * HW + q6 * 4 + j] = a[r][j] + bo;
        }
    }
    __syncthreads();

    if (t < HW) {
        float mx = -1e30f;
        for (int d = 0; d < D_; d++) mx = fmaxf(mx, ys[d * HW + t]);
        float s = 0.f;
        for (int d = 0; d < D_; d++) s = __fadd_rn(s, expf(__fsub_rn(ys[d * HW + t], mx)));
        smax[t] = mx; srs[t] = s;
    }
    __syncthreads();

    for (int u = t; u < D_ * HW; u += 256) {
        float yv = ys[u];
        int hw = u % HW;
        depth_ws[bn * PBN + u] = __fdiv_rn(expf(__fsub_rn(yv, smax[hw])), srs[hw]);
        dlogit[(size_t)bn * PBN + u] = yv;
    }
    for (int u = t; u < C_ * HW; u += 256)
        feat_ws[(size_t)bn * (C_ * HW) + u] = ys[D_ * HW + u];
}

// ---------------------------------------------------------------------------
// K2: geometry — BIT-FROZEN (validated). vox = ix*200 + iy or -1.
// ---------------------------------------------------------------------------
__global__ __launch_bounds__(256) void k_geom(
    const float* __restrict__ m1, const float* __restrict__ trans,
    const float* __restrict__ m2, int* __restrict__ vox)
{
    const float* rots = (fabsf(m1[0]) > 50.0f) ? m2 : m1;
    const float* intr = (fabsf(m1[0]) > 50.0f) ? m1 : m2;

    int p = blockIdx.x * 256 + threadIdx.x;   // 738*256 == 188928
    int b  = p / PPB;
    int pl = p % PPB;
    int n  = pl / PBN;
    int r  = pl % PBN;
    int d  = r / HW;
    int hw = r % HW;
    int h = hw / FW_, wp = hw % FW_;

    float dv = 4.0f + (float)d;
    float xi = (float)((double)wp * (199.0 / 5.0));
    float yi = (float)((double)h  * (149.0 / 3.0));
    float px = __fmul_rn(xi, dv), py = __fmul_rn(yi, dv), pz = dv;

    int bn = b * N_ + n;
    const float* K = intr + bn * 9;
    const float* R = rots + bn * 9;
    const float* T = trans + bn * 3;

    float a00 = K[0], a01 = K[1], a02 = K[2];
    float a11 = K[4], a12 = K[5];
    float a22 = K[8];

    float i00 = __fdiv_rn(1.0f, a00);
    float i11 = __fdiv_rn(1.0f, a11);
    float x0  = __fmul_rn(a01, i00);
    float i01 = __fmul_rn(-i11, x0);
    float i22 = __fdiv_rn(1.0f, a22);
    float y0  = __fmul_rn(a02, i00);
    y0 = __fadd_rn(y0, __fmul_rn(a12, i01));
    float y1  = __fmul_rn(a12, i11);
    float i02 = __fmul_rn(-i22, y0);
    float i12 = __fmul_rn(-i22, y1);
    float i10 = 0.f, i20 = 0.f, i21 = 0.f;

    float r00 = R[0], r01 = R[1], r02 = R[2];
    float r10 = R[3], r11 = R[4], r12 = R[5];
    float r20 = R[6], r21 = R[7], r22 = R[8];

#define MM(u0,u1,u2, v0,v1,v2) \
    __fmaf_rn(u2, v2, __fmaf_rn(u1, v1, __fmul_rn(u0, v0)))
    float c00 = MM(r00, r01, r02, i00, i10, i20);
    float c01 = MM(r00, r01, r02, i01, i11, i21);
    float c02 = MM(r00, r01, r02, i02, i12, i22);
    float c10 = MM(r10, r11, r12, i00, i10, i20);
    float c11 = MM(r10, r11, r12, i01, i11, i21);
    float c12 = MM(r10, r11, r12, i02, i12, i22);
    float c20 = MM(r20, r21, r22, i00, i10, i20);
    float c21 = MM(r20, r21, r22, i01, i11, i21);
    float c22 = MM(r20, r21, r22, i02, i12, i22);
#undef MM

#define DOT3(u0,v0,u1,v1,u2,v2) \
    __fadd_rn(__fadd_rn(__fmul_rn(u0,v0), __fmul_rn(u1,v1)), __fmul_rn(u2,v2))
    float gx = __fadd_rn(DOT3(c00,px, c01,py, c02,pz), T[0]);
    float gy = __fadd_rn(DOT3(c10,px, c11,py, c12,pz), T[1]);
    float gz = __fadd_rn(DOT3(c20,px, c21,py, c22,pz), T[2]);
#undef DOT3

    int ix = (int)__fmul_rn(__fadd_rn(gx, 50.0f), 2.0f);
    int iy = (int)__fmul_rn(__fadd_rn(gy, 50.0f), 2.0f);
    int iz = (int)__fdiv_rn(__fadd_rn(gz, 10.0f), 20.0f);
    bool kept = (ix >= 0) && (ix < 200) && (iy >= 0) && (iy < 200) && (iz == 0);
    vox[p] = kept ? (ix * 200 + iy) : -1;
}

// ---------------------------------------------------------------------------
// K3: splat -> f32 out (R17-validated form). One block per (b,c,quarter);
// 40KB LDS plane; LDS atomics; coalesced float4 stores.
// ---------------------------------------------------------------------------
__global__ __launch_bounds__(256) void k_splat(
    const float* __restrict__ depth, const float* __restrict__ feat,
    const int* __restrict__ vox, float* __restrict__ out)
{
    __shared__ float plane[10000];
    int bid = blockIdx.x;
    int b   = bid >> 8;
    int rem = bid & 255;
    int c   = rem >> 2;
    int q   = rem & 3;
    int t   = threadIdx.x;

    for (int i = t; i < 10000; i += 256) plane[i] = 0.f;
    __syncthreads();

    const int lo = q * 10000;
    const float* fb = feat + (size_t)(b * N_) * (C_ * HW) + c * HW;
    for (int i = t; i < PPB; i += 256) {
        int p = b * PPB + i;
        int rel = vox[p] - lo;
        if ((unsigned)rel < 10000u) {
            int n  = i / PBN;
            int hw = i % HW;              // 984 % 24 == 0
            atomicAdd(&plane[rel], depth[p] * fb[n * (C_ * HW) + hw]);
        }
    }
    __syncthreads();

    float4* ob = (float4*)(out + ((size_t)(b * C_ + c) * 40000) + lo);
    const float4* pl4 = (const float4*)plane;
    for (int i = t; i < 2500; i += 256) ob[i] = pl4[i];
}

// ---------------------------------------------------------------------------
extern "C" void kernel_launch(void* const* d_in, const int* in_sizes, int n_in,
                              void* d_out, int out_size, void* d_ws, size_t ws_size,
                              hipStream_t stream) {
    const float *x = nullptr, *m1 = nullptr, *m2 = nullptr, *trn = nullptr,
                *w = nullptr, *bias = nullptr;
    for (int i = 0; i < n_in; i++) {
        const float* p = (const float*)d_in[i];
        switch (in_sizes[i]) {
            case 3538944: x = p; break;
            case 1728:    if (!m1) m1 = p; else m2 = p; break;
            case 576:     trn = p; break;
            case 80640:   w = p; break;
            case 105:     bias = p; break;
            default: break;
        }
    }
    if (!x)    x    = (const float*)d_in[0];
    if (!m1)   m1   = (const float*)d_in[1];
    if (!trn)  trn  = (const float*)d_in[2];
    if (!m2)   m2   = (const float*)d_in[3];
    if (!w)    w    = (const float*)d_in[4];
    if (!bias) bias = (const float*)d_in[5];

    float* feat_ws  = (float*)d_ws;                 // 192*1536 f32
    float* depth_ws = feat_ws + 192 * C_ * HW;      // NPTS f32
    int*   vox      = (int*)(depth_ws + NPTS);      // NPTS i32

    float* out    = (float*)d_out;
    float* dlogit = out + FINAL_ELEMS;

    k_conv_fused<<<192,  256, 0, stream>>>(x, w, bias, feat_ws, depth_ws, dlogit);
    k_geom      <<<738,  256, 0, stream>>>(m1, trn, m2, vox);
    k_splat     <<<8192, 256, 0, stream>>>(depth_ws, feat_ws, vox, out);
}